// Round 12
// baseline (255.392 us; speedup 1.0000x reference)
//
#include <hip/hip_runtime.h>
#include <hip/hip_bf16.h>
#include <stdint.h>

#define NEG_INF -100000000.0f

typedef __attribute__((ext_vector_type(8))) short bf16x8;
typedef __attribute__((ext_vector_type(4))) float f32x4;
typedef __attribute__((ext_vector_type(4))) int i32x4;

// lgkm-only barrier: does NOT drain in-flight global (NT) stores/loads.
#define LGKM_BAR()                                                \
    do {                                                          \
        asm volatile("s_waitcnt lgkmcnt(0)" ::: "memory");        \
        __builtin_amdgcn_s_barrier();                             \
        __builtin_amdgcn_sched_barrier(0);                        \
    } while (0)

static __device__ __forceinline__ short f2bf(float x) {
    unsigned u = __float_as_uint(x);
    u = u + 0x7FFFu + ((u >> 16) & 1u);
    return (short)(u >> 16);
}

// ---------------- kernel 1: transpose + bf16-convert weights ----------------
__global__ void wtrans_kernel(const float* __restrict__ wq, const float* __restrict__ wk,
                              short* __restrict__ wtq, short* __restrict__ wtk) {
    __shared__ float tile[32][33];
    const float* w = blockIdx.z ? wk : wq;
    short* wt = blockIdx.z ? wtk : wtq;
    float scale = blockIdx.z ? 1.0f : 0.0625f;   // 1/sqrt(256) folded into wq
    int tx = threadIdx.x, ty = threadIdx.y;
    int c0 = blockIdx.x * 32;
    int k0 = blockIdx.y * 32;
#pragma unroll
    for (int i = 0; i < 4; i++)
        tile[ty + i * 8][tx] = w[(k0 + ty + i * 8) * 256 + c0 + tx];
    __syncthreads();
#pragma unroll
    for (int i = 0; i < 4; i++)
        wt[(c0 + ty + i * 8) * 256 + k0 + tx] = f2bf(tile[tx][ty + i * 8] * scale);
}

// ---------------- kernel 2: projection GEMM (pipelined) + (y==2) mask pack ----------------
// y=0: Q, y=1: K -> fragment layout [b][dc 8][row 1024][ks 32] bf16
// y=2: pack mask; word (row,j) bit (i*4+c) = mask[row][j*4+i*128+c]
__global__ __launch_bounds__(512, 4)
void proj_kernel(const float* __restrict__ qin, const float* __restrict__ kin,
                 const short* __restrict__ wtq, const short* __restrict__ wtk,
                 short* __restrict__ Qb, short* __restrict__ Kb,
                 const int* __restrict__ mask, unsigned* __restrict__ pmask) {
    if (blockIdx.y == 2) {
        int t = threadIdx.x;
        size_t row = (size_t)blockIdx.x * 64 + (t >> 3);
        int seg8 = t & 7;
        const int* mrow = mask + row * 1024;
#pragma unroll
        for (int jj = 0; jj < 4; jj++) {
            int j = seg8 + jj * 8;
            unsigned v = 0;
#pragma unroll
            for (int i = 0; i < 8; i++) {
                i32x4 x = __builtin_nontemporal_load(
                    reinterpret_cast<const i32x4*>(mrow + j * 4 + i * 128));
                unsigned nib = (unsigned)(x.x | (x.y << 1) | (x.z << 2) | (x.w << 3));
                v |= nib << (i * 4);
            }
            pmask[row * 32 + j] = v;
        }
        return;
    }

    const float* x  = blockIdx.y ? kin : qin;
    const short* wt = blockIdx.y ? wtk : wtq;
    short* outp     = blockIdx.y ? Kb  : Qb;

    __shared__ __align__(16) char slds[40960];     // 2 staging bufs / C-dump overlay
    short* xl0 = (short*)slds;          // [64 row][32 k]
    short* wl0 = xl0 + 2048;            // [256 c][32 k]
    short* xl1 = (short*)(slds + 20480);
    short* wl1 = xl1 + 2048;

    int t = threadIdx.x;
    int lane = t & 63, w = t >> 6;
    int l15 = lane & 15, g = lane >> 4;
    int rowbase = blockIdx.x * 64;

    int srow = t >> 3, sseg = t & 7;
    const float* xrow = x + (size_t)(rowbase + srow) * 256 + sseg * 4;
    int wc0 = t >> 2, wseg0 = t & 3;
    int wc1 = (512 + t) >> 2, wseg1 = t & 3;

    f32x4 zero = {0.f, 0.f, 0.f, 0.f};
    f32x4 acc[4][2];
#pragma unroll
    for (int m = 0; m < 4; m++)
#pragma unroll
        for (int n = 0; n < 2; n++) acc[m][n] = zero;

    {
        f32x4 xv = __builtin_nontemporal_load(reinterpret_cast<const f32x4*>(xrow));
        int4 wv0 = *reinterpret_cast<const int4*>(wt + wc0 * 256 + wseg0 * 8);
        int4 wv1 = *reinterpret_cast<const int4*>(wt + wc1 * 256 + wseg1 * 8);
        short4 bb; bb.x = f2bf(xv.x); bb.y = f2bf(xv.y); bb.z = f2bf(xv.z); bb.w = f2bf(xv.w);
        *reinterpret_cast<short4*>(&xl0[srow * 32 + sseg * 4]) = bb;
        *reinterpret_cast<int4*>(&wl0[(size_t)t * 8]) = wv0;
        *reinterpret_cast<int4*>(&wl0[((size_t)512 + t) * 8]) = wv1;
    }
    LGKM_BAR();

#pragma unroll
    for (int dc = 0; dc < 8; dc++) {
        short* xc   = (dc & 1) ? xl1 : xl0;
        short* wcur = (dc & 1) ? wl1 : wl0;
        short* xn   = (dc & 1) ? xl0 : xl1;
        short* wn   = (dc & 1) ? wl0 : wl1;

        f32x4 xv; int4 wv0, wv1;
        if (dc < 7) {
            xv  = __builtin_nontemporal_load(reinterpret_cast<const f32x4*>(xrow + (dc + 1) * 32));
            wv0 = *reinterpret_cast<const int4*>(wt + wc0 * 256 + (dc + 1) * 32 + wseg0 * 8);
            wv1 = *reinterpret_cast<const int4*>(wt + wc1 * 256 + (dc + 1) * 32 + wseg1 * 8);
        }

        bf16x8 a[4], bfr[2];
#pragma unroll
        for (int m = 0; m < 4; m++)
            a[m] = *reinterpret_cast<const bf16x8*>(&xc[(m * 16 + l15) * 32 + g * 8]);
#pragma unroll
        for (int n = 0; n < 2; n++) {
            int c = w * 32 + n * 16 + l15;
            bfr[n] = *reinterpret_cast<const bf16x8*>(&wcur[c * 32 + g * 8]);
        }
#pragma unroll
        for (int m = 0; m < 4; m++)
#pragma unroll
            for (int n = 0; n < 2; n++)
                acc[m][n] = __builtin_amdgcn_mfma_f32_16x16x32_bf16(a[m], bfr[n], acc[m][n], 0, 0, 0);

        if (dc < 7) {
            short4 bb; bb.x = f2bf(xv.x); bb.y = f2bf(xv.y); bb.z = f2bf(xv.z); bb.w = f2bf(xv.w);
            *reinterpret_cast<short4*>(&xn[srow * 32 + sseg * 4]) = bb;
            *reinterpret_cast<int4*>(&wn[(size_t)t * 8]) = wv0;
            *reinterpret_cast<int4*>(&wn[((size_t)512 + t) * 8]) = wv1;
            LGKM_BAR();
        }
    }

    LGKM_BAR();
    short* sdump = (short*)slds;    // [64 row][296]
#pragma unroll
    for (int m = 0; m < 4; m++)
#pragma unroll
        for (int n = 0; n < 2; n++) {
            int col = w * 32 + n * 16 + l15;
#pragma unroll
            for (int r = 0; r < 4; r++)
                sdump[(m * 16 + g * 4 + r) * 296 + col] = f2bf(acc[m][n][r]);
        }
    LGKM_BAR();

    int b8 = rowbase >> 10;
    int rloc = rowbase & 1023;
#pragma unroll
    for (int o = 0; o < 4; o++) {
        int gu = o * 512 + t;
        int dc = gu >> 8;
        int rem = gu & 255;
        int row = rem >> 2, kseg = rem & 3;
        int4 v = *reinterpret_cast<const int4*>(&sdump[row * 296 + dc * 32 + kseg * 8]);
        size_t idx = (((size_t)b8 * 8 + dc) * 1024 + rloc + row) * 32 + kseg * 8;
        *reinterpret_cast<int4*>(outp + idx) = v;
    }
}

// ---------------- kernel 3: persistent-pipelined fused attention ----------------
// 512 blocks (2/CU, whole grid resident), each owns 4 consecutive 32-row q-tiles
// of ONE batch. Steady state: QK^T(tile i+1) [global loads, vmcnt] interleaved
// with epilogue pass-1(tile i) [LDS park, lgkmcnt] in one stream; NT stores fly
// across lgkm-only barriers.
__global__ __launch_bounds__(512, 4)
void attn_kernel(const short* __restrict__ Qs, const short* __restrict__ Ks,
                 const unsigned* __restrict__ pmask, float* __restrict__ out) {
    const int RSB = 1048;                            // shorts/row: 16B-aligned rows, <=2-way banks
    __shared__ __align__(16) short park[32 * RSB];   // 67,072 B -> 2 blocks/CU

    int t = threadIdx.x;
    int lane = t & 63, w = t >> 6;
    int l15 = lane & 15, g = lane >> 4;
    int prow = t >> 4, j16 = t & 15;   // epilogue: 16 threads per park row

    int bid = blockIdx.x;
    int b = (bid & 7) * 8 + ((bid >> 3) >> 3);       // XCD-major: 8 batches per XCD
    int brow0 = ((bid >> 3) & 7) * 128;              // block's 4-tile span

    const short* qb = Qs + (size_t)b * 262144;
    const short* kb = Ks + (size_t)b * 262144;
    const unsigned* pmb = pmask + (size_t)b * 32768;

    f32x4 zero = {0.f, 0.f, 0.f, 0.f};
    f32x4 acc[2][8];
#pragma unroll
    for (int m = 0; m < 2; m++)
#pragma unroll
        for (int n = 0; n < 8; n++) acc[m][n] = zero;

    // mask words for tile 0 (row brow0+prow, cols j16*8 + i*128 span)
    uint2 mw = *reinterpret_cast<const uint2*>(pmb + (size_t)(brow0 + prow) * 32 + j16 * 2);

    // ---- prologue: QK^T tile 0 ----
    for (int dc = 0; dc < 8; dc++) {
        const short* qc = qb + dc * 32768;
        const short* kc = kb + dc * 32768;
        bf16x8 a0 = *reinterpret_cast<const bf16x8*>(qc + (brow0 + l15) * 32 + g * 8);
        bf16x8 a1 = *reinterpret_cast<const bf16x8*>(qc + (brow0 + 16 + l15) * 32 + g * 8);
#pragma unroll
        for (int n = 0; n < 8; n++) {
            bf16x8 bf = *reinterpret_cast<const bf16x8*>(kc + (w * 128 + n * 16 + l15) * 32 + g * 8);
            acc[0][n] = __builtin_amdgcn_mfma_f32_16x16x32_bf16(a0, bf, acc[0][n], 0, 0, 0);
            acc[1][n] = __builtin_amdgcn_mfma_f32_16x16x32_bf16(a1, bf, acc[1][n], 0, 0, 0);
        }
    }
#pragma unroll
    for (int m = 0; m < 2; m++)
#pragma unroll
        for (int n = 0; n < 8; n++) {
#pragma unroll
            for (int r = 0; r < 4; r++)
                park[(m * 16 + g * 4 + r) * RSB + w * 128 + n * 16 + l15] = f2bf(acc[m][n][r]);
            acc[m][n] = zero;
        }
    LGKM_BAR();

    // ---- 4-tile pipeline ----
    for (int i = 0; i < 4; ++i) {
        int brow_i = brow0 + i * 32;
        int brow_n = brow_i + 32;
        uint2 mwn;
        if (i < 3)
            mwn = *reinterpret_cast<const uint2*>(pmb + (size_t)(brow_n + prow) * 32 + j16 * 2);

        float psum = 0.f;
        short* urow = park + prow * RSB;
        for (int dc = 0; dc < 8; ++dc) {
            if (i < 3) {   // QK^T chunk for tile i+1 (vmcnt domain)
                const short* qc = qb + dc * 32768;
                const short* kc = kb + dc * 32768;
                bf16x8 a0 = *reinterpret_cast<const bf16x8*>(qc + (brow_n + l15) * 32 + g * 8);
                bf16x8 a1 = *reinterpret_cast<const bf16x8*>(qc + (brow_n + 16 + l15) * 32 + g * 8);
#pragma unroll
                for (int n = 0; n < 8; n++) {
                    bf16x8 bf = *reinterpret_cast<const bf16x8*>(kc + (w * 128 + n * 16 + l15) * 32 + g * 8);
                    acc[0][n] = __builtin_amdgcn_mfma_f32_16x16x32_bf16(a0, bf, acc[0][n], 0, 0, 0);
                    acc[1][n] = __builtin_amdgcn_mfma_f32_16x16x32_bf16(a1, bf, acc[1][n], 0, 0, 0);
                }
            }
            // epilogue pass-1 chunk for tile i (lgkmcnt domain)
            int c0 = j16 * 8 + dc * 128;
            i32x4 raw = *reinterpret_cast<const i32x4*>(urow + c0);
            unsigned blo = (mw.x >> (dc * 4)) & 0xFu;
            unsigned bhi = (mw.y >> (dc * 4)) & 0xFu;
            unsigned rw0 = (unsigned)raw.x, rw1 = (unsigned)raw.y;
            unsigned rw2 = (unsigned)raw.z, rw3 = (unsigned)raw.w;
            unsigned ow[4];
            unsigned rws[4] = {rw0, rw1, rw2, rw3};
#pragma unroll
            for (int h = 0; h < 4; h++) {
                float u0 = __uint_as_float(rws[h] << 16);
                float u1 = __uint_as_float(rws[h] & 0xffff0000u);
                unsigned bb2 = (h < 2) ? (blo >> (h * 2)) : (bhi >> ((h - 2) * 2));
                float e20 = __expf(2.0f * u0), e21 = __expf(2.0f * u1);
                float t0 = 10.0f - 20.0f / (e20 + 1.0f);
                float t1 = 10.0f - 20.0f / (e21 + 1.0f);
                bool m0 = bb2 & 1, m1 = (bb2 >> 1) & 1;
                float uc0 = m0 ? NEG_INF : t0;
                float uc1 = m1 ? NEG_INF : t1;
                psum += m0 ? 0.0f : __expf(t0);
                psum += m1 ? 0.0f : __expf(t1);
                ow[h] = ((unsigned)(unsigned short)f2bf(uc0)) |
                        (((unsigned)(unsigned short)f2bf(uc1)) << 16);
            }
            i32x4 o = {(int)ow[0], (int)ow[1], (int)ow[2], (int)ow[3]};
            *reinterpret_cast<i32x4*>(urow + c0) = o;
        }

        // row-sum over the 16 threads sharing this park row
        psum += __shfl_xor(psum, 1);
        psum += __shfl_xor(psum, 2);
        psum += __shfl_xor(psum, 4);
        psum += __shfl_xor(psum, 8);
        float lse = __logf(fmaxf(psum, 1e-30f));

        // pass 2: wave w owns park rows 4w..4w+3; full-wave NT stores
        float* obase = out + ((size_t)b * 1024 + brow_i) * 1024;
#pragma unroll
        for (int rr = 0; rr < 4; rr++) {
            int r2 = w * 4 + rr;
            float lser = __shfl(lse, rr * 16);
            const short* ur2 = park + r2 * RSB;
            float* orow = obase + (size_t)r2 * 1024;
#pragma unroll
            for (int seg = 0; seg < 4; seg++) {
                int col = lane * 4 + seg * 256;
                unsigned lo = *reinterpret_cast<const unsigned*>(ur2 + col);
                unsigned hi = *reinterpret_cast<const unsigned*>(ur2 + col + 2);
                f32x4 o = {__uint_as_float(lo << 16) - lser,
                           __uint_as_float(lo & 0xffff0000u) - lser,
                           __uint_as_float(hi << 16) - lser,
                           __uint_as_float(hi & 0xffff0000u) - lser};
                __builtin_nontemporal_store(o, reinterpret_cast<f32x4*>(orow + col));
            }
        }

        LGKM_BAR();                 // all park reads done; NT stores keep flying
        if (i < 3) {                // dump tile i+1, reset acc, advance mask
#pragma unroll
            for (int m = 0; m < 2; m++)
#pragma unroll
                for (int n = 0; n < 8; n++) {
#pragma unroll
                    for (int r = 0; r < 4; r++)
                        park[(m * 16 + g * 4 + r) * RSB + w * 128 + n * 16 + l15] = f2bf(acc[m][n][r]);
                    acc[m][n] = zero;
                }
            mw = mwn;
        }
        LGKM_BAR();                 // dump visible before next pass-1
    }
}

extern "C" void kernel_launch(void* const* d_in, const int* in_sizes, int n_in,
                              void* d_out, int out_size, void* d_ws, size_t ws_size,
                              hipStream_t stream) {
    const float* q  = (const float*)d_in[0];
    const float* k  = (const float*)d_in[1];
    const float* wq = (const float*)d_in[2];
    const float* wk = (const float*)d_in[3];
    const int* mask = (const int*)d_in[4];
    float* out = (float*)d_out;

    char* ws = (char*)d_ws;
    short* wtq = (short*)ws;                                   // 128KB
    short* wtk = (short*)(ws + 131072);                        // 128KB
    short* Qb  = (short*)(ws + 262144);                        // 32MB
    short* Kb  = (short*)(ws + 262144 + 33554432);             // 32MB
    unsigned* pmask = (unsigned*)(ws + 262144 + 2 * 33554432); // 8.4MB

    wtrans_kernel<<<dim3(8, 8, 2), dim3(32, 8), 0, stream>>>(wq, wk, wtq, wtk);
    proj_kernel<<<dim3(1024, 3), 512, 0, stream>>>(q, k, wtq, wtk, Qb, Kb, mask, pmask);
    attn_kernel<<<dim3(512), 512, 0, stream>>>(Qb, Kb, pmask, out);
}

// Round 13
// 220.470 us; speedup vs baseline: 1.1584x; 1.1584x over previous
//
#include <hip/hip_runtime.h>
#include <hip/hip_bf16.h>
#include <stdint.h>

#define NEG_INF -100000000.0f

typedef __attribute__((ext_vector_type(8))) short bf16x8;
typedef __attribute__((ext_vector_type(4))) float f32x4;
typedef __attribute__((ext_vector_type(4))) int i32x4;

// lgkm-only barrier: does NOT drain in-flight global (NT) stores/loads.
#define LGKM_BAR()                                                \
    do {                                                          \
        asm volatile("s_waitcnt lgkmcnt(0)" ::: "memory");        \
        __builtin_amdgcn_s_barrier();                             \
        __builtin_amdgcn_sched_barrier(0);                        \
    } while (0)

static __device__ __forceinline__ short f2bf(float x) {
    unsigned u = __float_as_uint(x);
    u = u + 0x7FFFu + ((u >> 16) & 1u);
    return (short)(u >> 16);
}

// ---------------- kernel 1: transpose + bf16-convert weights ----------------
__global__ void wtrans_kernel(const float* __restrict__ wq, const float* __restrict__ wk,
                              short* __restrict__ wtq, short* __restrict__ wtk) {
    __shared__ float tile[32][33];
    const float* w = blockIdx.z ? wk : wq;
    short* wt = blockIdx.z ? wtk : wtq;
    float scale = blockIdx.z ? 1.0f : 0.0625f;   // 1/sqrt(256) folded into wq
    int tx = threadIdx.x, ty = threadIdx.y;
    int c0 = blockIdx.x * 32;
    int k0 = blockIdx.y * 32;
#pragma unroll
    for (int i = 0; i < 4; i++)
        tile[ty + i * 8][tx] = w[(k0 + ty + i * 8) * 256 + c0 + tx];
    __syncthreads();
#pragma unroll
    for (int i = 0; i < 4; i++)
        wt[(c0 + ty + i * 8) * 256 + k0 + tx] = f2bf(tile[tx][ty + i * 8] * scale);
}

// ---------------- kernel 2: projection GEMM (pipelined) + (y==2) fragment-layout mask pack ----------------
// y=0: Q, y=1: K -> fragment layout [b][dc 8][row 1024][ks 32] bf16
// y=2: pack mask into MFMA-fragment-layout bit words:
//   word for (tile, m, w_o, lane_o), bit (r*8+n) = mask[tile*32+m*16+(lane_o>>4)*4+r][w_o*128+n*16+(lane_o&15)]
__global__ __launch_bounds__(512, 4)
void proj_kernel(const float* __restrict__ qin, const float* __restrict__ kin,
                 const short* __restrict__ wtq, const short* __restrict__ wtk,
                 short* __restrict__ Qb, short* __restrict__ Kb,
                 const int* __restrict__ mask, unsigned* __restrict__ pmask) {
    __shared__ __align__(16) char slds[40960];     // staging bufs / C-dump / mask-word overlay

    if (blockIdx.y == 2) {
        unsigned* words = (unsigned*)slds;         // [64 row][33]
        int t = threadIdx.x;
        int row = t >> 3, seg8 = t & 7;
        size_t grow = (size_t)blockIdx.x * 64 + row;
        const int* mrow = mask + grow * 1024;
        // phase A: row-major pack -> LDS. word(row,j) bit (i*4+c) = mask[row][j*4+i*128+c]
#pragma unroll
        for (int jj = 0; jj < 4; jj++) {
            int j = seg8 + jj * 8;
            unsigned v = 0;
#pragma unroll
            for (int i = 0; i < 8; i++) {
                i32x4 x = __builtin_nontemporal_load(
                    reinterpret_cast<const i32x4*>(mrow + j * 4 + i * 128));
                unsigned nib = (unsigned)(x.x | (x.y << 1) | (x.z << 2) | (x.w << 3));
                v |= nib << (i * 4);
            }
            words[row * 33 + j] = v;
        }
        __syncthreads();
        // phase B: bit-transpose to fragment layout
        int w_o = t >> 6, lane_o = t & 63;
        int g_o = lane_o >> 4, l15 = lane_o & 15;
        int bitpos = w_o * 4 + (l15 & 3);
        int jb = l15 >> 2;
        unsigned* obase = pmask + (size_t)blockIdx.x * 2048;   // 2 tiles * 1024 words
#pragma unroll
        for (int tt = 0; tt < 2; tt++)
#pragma unroll
            for (int mm = 0; mm < 2; mm++) {
                unsigned v = 0;
#pragma unroll
                for (int r = 0; r < 4; r++) {
                    int rrow = tt * 32 + mm * 16 + g_o * 4 + r;
#pragma unroll
                    for (int n = 0; n < 8; n++) {
                        unsigned bit = (words[rrow * 33 + n * 4 + jb] >> bitpos) & 1u;
                        v |= bit << (r * 8 + n);
                    }
                }
                obase[tt * 1024 + mm * 512 + t] = v;
            }
        return;
    }

    const float* x  = blockIdx.y ? kin : qin;
    const short* wt = blockIdx.y ? wtk : wtq;
    short* outp     = blockIdx.y ? Kb  : Qb;

    short* xl0 = (short*)slds;          // [64 row][32 k]
    short* wl0 = xl0 + 2048;            // [256 c][32 k]
    short* xl1 = (short*)(slds + 20480);
    short* wl1 = xl1 + 2048;

    int t = threadIdx.x;
    int lane = t & 63, w = t >> 6;
    int l15 = lane & 15, g = lane >> 4;
    int rowbase = blockIdx.x * 64;

    int srow = t >> 3, sseg = t & 7;
    const float* xrow = x + (size_t)(rowbase + srow) * 256 + sseg * 4;
    int wc0 = t >> 2, wseg0 = t & 3;
    int wc1 = (512 + t) >> 2, wseg1 = t & 3;

    f32x4 zero = {0.f, 0.f, 0.f, 0.f};
    f32x4 acc[4][2];
#pragma unroll
    for (int m = 0; m < 4; m++)
#pragma unroll
        for (int n = 0; n < 2; n++) acc[m][n] = zero;

    {
        f32x4 xv = __builtin_nontemporal_load(reinterpret_cast<const f32x4*>(xrow));
        int4 wv0 = *reinterpret_cast<const int4*>(wt + wc0 * 256 + wseg0 * 8);
        int4 wv1 = *reinterpret_cast<const int4*>(wt + wc1 * 256 + wseg1 * 8);
        short4 bb; bb.x = f2bf(xv.x); bb.y = f2bf(xv.y); bb.z = f2bf(xv.z); bb.w = f2bf(xv.w);
        *reinterpret_cast<short4*>(&xl0[srow * 32 + sseg * 4]) = bb;
        *reinterpret_cast<int4*>(&wl0[(size_t)t * 8]) = wv0;
        *reinterpret_cast<int4*>(&wl0[((size_t)512 + t) * 8]) = wv1;
    }
    LGKM_BAR();

#pragma unroll
    for (int dc = 0; dc < 8; dc++) {
        short* xc   = (dc & 1) ? xl1 : xl0;
        short* wcur = (dc & 1) ? wl1 : wl0;
        short* xn   = (dc & 1) ? xl0 : xl1;
        short* wn   = (dc & 1) ? wl0 : wl1;

        f32x4 xv; int4 wv0, wv1;
        if (dc < 7) {
            xv  = __builtin_nontemporal_load(reinterpret_cast<const f32x4*>(xrow + (dc + 1) * 32));
            wv0 = *reinterpret_cast<const int4*>(wt + wc0 * 256 + (dc + 1) * 32 + wseg0 * 8);
            wv1 = *reinterpret_cast<const int4*>(wt + wc1 * 256 + (dc + 1) * 32 + wseg1 * 8);
        }

        bf16x8 a[4], bfr[2];
#pragma unroll
        for (int m = 0; m < 4; m++)
            a[m] = *reinterpret_cast<const bf16x8*>(&xc[(m * 16 + l15) * 32 + g * 8]);
#pragma unroll
        for (int n = 0; n < 2; n++) {
            int c = w * 32 + n * 16 + l15;
            bfr[n] = *reinterpret_cast<const bf16x8*>(&wcur[c * 32 + g * 8]);
        }
#pragma unroll
        for (int m = 0; m < 4; m++)
#pragma unroll
            for (int n = 0; n < 2; n++)
                acc[m][n] = __builtin_amdgcn_mfma_f32_16x16x32_bf16(a[m], bfr[n], acc[m][n], 0, 0, 0);

        if (dc < 7) {
            short4 bb; bb.x = f2bf(xv.x); bb.y = f2bf(xv.y); bb.z = f2bf(xv.z); bb.w = f2bf(xv.w);
            *reinterpret_cast<short4*>(&xn[srow * 32 + sseg * 4]) = bb;
            *reinterpret_cast<int4*>(&wn[(size_t)t * 8]) = wv0;
            *reinterpret_cast<int4*>(&wn[((size_t)512 + t) * 8]) = wv1;
            LGKM_BAR();
        }
    }

    LGKM_BAR();
    short* sdump = (short*)slds;    // [64 row][296]
#pragma unroll
    for (int m = 0; m < 4; m++)
#pragma unroll
        for (int n = 0; n < 2; n++) {
            int col = w * 32 + n * 16 + l15;
#pragma unroll
            for (int r = 0; r < 4; r++)
                sdump[(m * 16 + g * 4 + r) * 296 + col] = f2bf(acc[m][n][r]);
        }
    LGKM_BAR();

    int b8 = rowbase >> 10;
    int rloc = rowbase & 1023;
#pragma unroll
    for (int o = 0; o < 4; o++) {
        int gu = o * 512 + t;
        int dc = gu >> 8;
        int rem = gu & 255;
        int row = rem >> 2, kseg = rem & 3;
        int4 v = *reinterpret_cast<const int4*>(&sdump[row * 296 + dc * 32 + kseg * 8]);
        size_t idx = (((size_t)b8 * 8 + dc) * 1024 + rloc + row) * 32 + kseg * 8;
        *reinterpret_cast<int4*>(outp + idx) = v;
    }
}

// ---------------- kernel 3: fused QK^T + tanh-clip + mask + log_softmax ----------------
// R8 skeleton + in-register pass-1: transform+row-sum directly on acc fragments
// (fragment-layout packed mask), dump transformed uc (bf16) to park, ONE barrier,
// then full-row float4 NT stores for both halves.
__global__ __launch_bounds__(512, 4)
void attn_kernel(const short* __restrict__ Qs, const short* __restrict__ Ks,
                 const unsigned* __restrict__ pmf, float* __restrict__ out) {
    const int RSB = 1034;                              // shorts/row: <=2-way banks
    __shared__ __align__(16) short park[32 * RSB];     // 66,176 B
    __shared__ float redbuf[32 * 8];                   // [park row][wave] partial sums

    int t = threadIdx.x;
    int lane = t & 63, w = t >> 6;
    int l15 = lane & 15, g = lane >> 4;

    int bid = blockIdx.x;
    int wg = (bid & 7) * 256 + (bid >> 3);   // XCD swizzle
    int b = wg >> 5;
    int qt = wg & 31;
    int brow = qt * 32;

    // fragment-layout packed mask: 2 words/thread, prefetched behind QK^T
    const unsigned* pm = pmf + (size_t)(b * 32 + qt) * 1024;
    unsigned mw0 = pm[t];
    unsigned mw1 = pm[512 + t];

    const short* qb = Qs + (size_t)b * 8 * 32768;
    const short* kb = Ks + (size_t)b * 8 * 32768;

    f32x4 zero = {0.f, 0.f, 0.f, 0.f};
    f32x4 acc[2][8];
#pragma unroll
    for (int m = 0; m < 2; m++)
#pragma unroll
        for (int n = 0; n < 8; n++) acc[m][n] = zero;

    for (int dc = 0; dc < 8; dc++) {
        const short* qc = qb + dc * 32768;
        const short* kc = kb + dc * 32768;
        bf16x8 a0 = *reinterpret_cast<const bf16x8*>(qc + (brow + l15) * 32 + g * 8);
        bf16x8 a1 = *reinterpret_cast<const bf16x8*>(qc + (brow + 16 + l15) * 32 + g * 8);
#pragma unroll
        for (int n = 0; n < 8; n++) {
            bf16x8 bf = *reinterpret_cast<const bf16x8*>(kc + (w * 128 + n * 16 + l15) * 32 + g * 8);
            acc[0][n] = __builtin_amdgcn_mfma_f32_16x16x32_bf16(a0, bf, acc[0][n], 0, 0, 0);
            acc[1][n] = __builtin_amdgcn_mfma_f32_16x16x32_bf16(a1, bf, acc[1][n], 0, 0, 0);
        }
    }

    // ---- in-register pass 1: tanh-clip + mask + exp-sum; dump uc (bf16) to park ----
    float rowsum[2][4];
#pragma unroll
    for (int m = 0; m < 2; m++)
#pragma unroll
        for (int r = 0; r < 4; r++) rowsum[m][r] = 0.f;

#pragma unroll
    for (int m = 0; m < 2; m++) {
        unsigned bits = m ? mw1 : mw0;
#pragma unroll
        for (int n = 0; n < 8; n++)
#pragma unroll
            for (int r = 0; r < 4; r++) {
                float u = acc[m][n][r];
                float e2 = __expf(2.0f * u);
                float tc = 10.0f - 20.0f / (e2 + 1.0f);   // 10*tanh(u)
                bool msk = (bits >> (r * 8 + n)) & 1;
                float uc = msk ? NEG_INF : tc;
                rowsum[m][r] += msk ? 0.0f : __expf(tc);
                park[(m * 16 + g * 4 + r) * RSB + w * 128 + n * 16 + l15] = f2bf(uc);
            }
    }

    // reduce over the 16 lanes sharing each row; lane l15==0 publishes partials
#pragma unroll
    for (int m = 0; m < 2; m++)
#pragma unroll
        for (int r = 0; r < 4; r++) {
            float s = rowsum[m][r];
            s += __shfl_xor(s, 1);
            s += __shfl_xor(s, 2);
            s += __shfl_xor(s, 4);
            s += __shfl_xor(s, 8);
            rowsum[m][r] = s;
        }
    if (l15 == 0) {
#pragma unroll
        for (int m = 0; m < 2; m++)
#pragma unroll
            for (int r = 0; r < 4; r++)
                redbuf[(m * 16 + g * 4 + r) * 8 + w] = rowsum[m][r];
    }
    LGKM_BAR();   // park + redbuf visible; NT stores (none yet) unaffected

    // ---- pass 2: per park row: lse from 8 partials, full-wave NT row stores ----
#pragma unroll
    for (int m = 0; m < 2; m++)
#pragma unroll
        for (int rr = 0; rr < 2; rr++) {
            int pr = m * 16 + w * 2 + rr;                  // park row this wave owns
            const float4* rb = reinterpret_cast<const float4*>(&redbuf[pr * 8]);
            float4 s0 = rb[0], s1 = rb[1];
            float ssum = ((s0.x + s0.y) + (s0.z + s0.w)) + ((s1.x + s1.y) + (s1.z + s1.w));
            float lser = __logf(fmaxf(ssum, 1e-30f));
            const short* ur2 = park + pr * RSB;
            float* orow = out + ((size_t)b * 1024 + brow + pr) * 1024;
#pragma unroll
            for (int seg = 0; seg < 4; seg++) {
                int col = lane * 4 + seg * 256;
                unsigned lo = *reinterpret_cast<const unsigned*>(&ur2[col]);
                unsigned hi = *reinterpret_cast<const unsigned*>(&ur2[col + 2]);
                f32x4 o = {__uint_as_float(lo << 16) - lser,
                           __uint_as_float(lo & 0xffff0000u) - lser,
                           __uint_as_float(hi << 16) - lser,
                           __uint_as_float(hi & 0xffff0000u) - lser};
                __builtin_nontemporal_store(o, reinterpret_cast<f32x4*>(orow + col));
            }
        }
}

extern "C" void kernel_launch(void* const* d_in, const int* in_sizes, int n_in,
                              void* d_out, int out_size, void* d_ws, size_t ws_size,
                              hipStream_t stream) {
    const float* q  = (const float*)d_in[0];
    const float* k  = (const float*)d_in[1];
    const float* wq = (const float*)d_in[2];
    const float* wk = (const float*)d_in[3];
    const int* mask = (const int*)d_in[4];
    float* out = (float*)d_out;

    char* ws = (char*)d_ws;
    short* wtq = (short*)ws;                                   // 128KB
    short* wtk = (short*)(ws + 131072);                        // 128KB
    short* Qb  = (short*)(ws + 262144);                        // 32MB
    short* Kb  = (short*)(ws + 262144 + 33554432);             // 32MB
    unsigned* pmask = (unsigned*)(ws + 262144 + 2 * 33554432); // 8.4MB

    wtrans_kernel<<<dim3(8, 8, 2), dim3(32, 8), 0, stream>>>(wq, wk, wtq, wtk);
    proj_kernel<<<dim3(1024, 3), 512, 0, stream>>>(q, k, wtq, wtk, Qb, Kb, mask, pmask);
    attn_kernel<<<dim3(2048), 512, 0, stream>>>(Qb, Kb, pmask, out);
}